// Round 8
// baseline (1213.427 us; speedup 1.0000x reference)
//
#include <hip/hip_runtime.h>
#include <stdint.h>

#define DIM  2048
#define NEXP 8
#define NH   1408
#define NHS  2816
#define NT   8192
#define NA   (NT*2)

typedef unsigned short u16;
typedef short bf16x8 __attribute__((ext_vector_type(8)));
typedef float f32x4 __attribute__((ext_vector_type(4)));

typedef __attribute__((address_space(1))) const uint32_t gas_u32;
typedef __attribute__((address_space(3))) uint32_t las_u32;

__device__ __forceinline__ u16 f2bf(float f) {
  uint32_t x = __builtin_bit_cast(uint32_t, f);
  x += 0x7FFFu + ((x >> 16) & 1u);
  return (u16)(x >> 16);
}

__device__ __forceinline__ void gload_lds16(const void* g, void* l) {
  __builtin_amdgcn_global_load_lds((gas_u32*)g, (las_u32*)l, 16, 0, 0);
}

struct alignas(16) US8 { u16 u[8]; };
struct alignas(8)  US4 { u16 u[4]; };

// ---------------- fp32 -> bf16 conversion ----------------
__global__ __launch_bounds__(256) void convert_kernel(const float* __restrict__ src,
                                                      u16* __restrict__ dst, int n8) {
  int i = blockIdx.x * 256 + threadIdx.x;
  if (i >= n8) return;
  const float4* s = (const float4*)src + (size_t)i * 2;
  float4 a = s[0], b = s[1];
  US8 r;
  r.u[0]=f2bf(a.x); r.u[1]=f2bf(a.y); r.u[2]=f2bf(a.z); r.u[3]=f2bf(a.w);
  r.u[4]=f2bf(b.x); r.u[5]=f2bf(b.y); r.u[6]=f2bf(b.z); r.u[7]=f2bf(b.w);
  *((US8*)dst + i) = r;
}

// interleave rows: dst row (2*srcrow + par); inner dim 2048 -> 256 groups of 8.
__global__ __launch_bounds__(256) void convert_ilv(const float* __restrict__ src,
                                                   u16* __restrict__ dst, int n8, int par) {
  int i = blockIdx.x * 256 + threadIdx.x;
  if (i >= n8) return;
  int row = i >> 8, c = i & 255;
  const float4* s = (const float4*)src + (size_t)i * 2;
  float4 a = s[0], b = s[1];
  US8 r;
  r.u[0]=f2bf(a.x); r.u[1]=f2bf(a.y); r.u[2]=f2bf(a.z); r.u[3]=f2bf(a.w);
  r.u[4]=f2bf(b.x); r.u[5]=f2bf(b.y); r.u[6]=f2bf(b.z); r.u[7]=f2bf(b.w);
  *((US8*)dst + (((size_t)(2*row + par)) << 8) + c) = r;
}

// ---------------- router (fused x->bf16 emit) ----------------
__global__ void zero_counts(int* counts) { if (threadIdx.x < NEXP) counts[threadIdx.x] = 0; }

__global__ __launch_bounds__(64) void router_kernel(const float* __restrict__ x,
    const float* __restrict__ gw, const float* __restrict__ gb,
    u16* __restrict__ xb,
    int* __restrict__ tope, float* __restrict__ topw, int* __restrict__ counts) {
  const int t = blockIdx.x;
  const int lane = threadIdx.x;
  const float4* xr = (const float4*)(x + (size_t)t * DIM);
  float4 xv[8];
  #pragma unroll
  for (int j = 0; j < 8; j++) xv[j] = xr[j * 64 + lane];
  US4* xrow = (US4*)(xb + (size_t)t * DIM);
  #pragma unroll
  for (int j = 0; j < 8; j++) {
    US4 r4;
    r4.u[0] = f2bf(xv[j].x); r4.u[1] = f2bf(xv[j].y);
    r4.u[2] = f2bf(xv[j].z); r4.u[3] = f2bf(xv[j].w);
    xrow[j * 64 + lane] = r4;
  }
  float p[NEXP];
  #pragma unroll
  for (int e = 0; e < NEXP; e++) {
    const float4* gr = (const float4*)(gw + (size_t)e * DIM);
    float s = 0.f;
    #pragma unroll
    for (int j = 0; j < 8; j++) {
      float4 g = gr[j * 64 + lane];
      s += xv[j].x*g.x + xv[j].y*g.y + xv[j].z*g.z + xv[j].w*g.w;
    }
    p[e] = s;
  }
  #pragma unroll
  for (int off = 32; off > 0; off >>= 1) {
    #pragma unroll
    for (int e = 0; e < NEXP; e++) p[e] += __shfl_xor(p[e], off);
  }
  if (lane == 0) {
    float pr[NEXP];
    float mx = -1e30f;
    #pragma unroll
    for (int e = 0; e < NEXP; e++) { p[e] += gb[e]; mx = fmaxf(mx, p[e]); }
    float den = 0.f;
    #pragma unroll
    for (int e = 0; e < NEXP; e++) { pr[e] = __expf(p[e] - mx); den += pr[e]; }
    float inv = 1.f / den;
    #pragma unroll
    for (int e = 0; e < NEXP; e++) pr[e] *= inv;
    int e0 = 0;
    #pragma unroll
    for (int e = 1; e < NEXP; e++) if (pr[e] > pr[e0]) e0 = e;
    int e1 = (e0 == 0) ? 1 : 0;
    #pragma unroll
    for (int e = 0; e < NEXP; e++) { if (e != e0 && pr[e] > pr[e1]) e1 = e; }
    tope[t*2]   = e0; tope[t*2+1] = e1;
    topw[t*2]   = pr[e0]; topw[t*2+1] = pr[e1];
    atomicAdd(&counts[e0], 1); atomicAdd(&counts[e1], 1);
  }
}

__global__ void scan_kernel(const int* __restrict__ counts, int* __restrict__ offsets,
                            int* __restrict__ cursor) {
  if (threadIdx.x == 0) {
    int s = 0;
    for (int e = 0; e < NEXP; e++) { offsets[e] = s; cursor[e] = s; s += counts[e]; }
    offsets[NEXP] = s;
  }
}

__global__ __launch_bounds__(256) void assign_kernel(const int* __restrict__ tope,
    const float* __restrict__ topw, int* __restrict__ cursor,
    int* __restrict__ ptok, float* __restrict__ pw) {
  int t = blockIdx.x * 256 + threadIdx.x;
  if (t >= NT) return;
  #pragma unroll
  for (int k = 0; k < 2; k++) {
    int e = tope[t*2+k];
    int pos = atomicAdd(&cursor[e], 1);
    ptok[pos] = t;
    pw[pos]   = topw[t*2+k];
  }
}

// ---------------- 256x256 8-phase up-GEMM: C = A * B^T, fused SwiGLU ----------------
// EPI 0 = shared up (interleaved g/u cols), 1 = routed up (gathered A, +bias, *pw)
#define BAR() { asm volatile("" ::: "memory"); __builtin_amdgcn_s_barrier(); asm volatile("" ::: "memory"); }
#define VM6 asm volatile("s_waitcnt vmcnt(6)" ::: "memory")
#define VM0 asm volatile("s_waitcnt vmcnt(0)" ::: "memory")
#define LGKM8 asm volatile("s_waitcnt lgkmcnt(8)" ::: "memory")

template<int EPI>
__global__ __launch_bounds__(512, 2) void gemm8(
    const u16* __restrict__ A, const u16* __restrict__ Bw, u16* __restrict__ Hout,
    const float* __restrict__ biasG, const float* __restrict__ biasU,
    const int* __restrict__ offsets, const int* __restrict__ ptok,
    const float* __restrict__ pw, int M, int N, int K, int Hf)
{
  constexpr bool SEG = (EPI == 1);
  extern __shared__ char smem[];
  const int nt = blockIdx.x, mt = blockIdx.y;
  int e = 0, seg = 0, cnt = M;
  if (SEG) { e = blockIdx.z; seg = offsets[e]; cnt = offsets[e+1] - seg; if (mt*256 >= cnt) return; }
  const int tid = threadIdx.x, wave = tid >> 6, lane = tid & 63;
  const int NKT = K >> 6;

  // per-thread staging sources (chunk pre-inverse-swizzled; LDS dest linear)
  const u16* Bp = Bw + (SEG ? (size_t)e * (size_t)N * K : (size_t)0);
  const u16* sAp[2][2]; const u16* sBp[2][2];
  {
    const int trow = tid >> 3;
    const int tch  = (tid & 7) ^ (trow & 7);
    #pragma unroll
    for (int h = 0; h < 2; h++)
      #pragma unroll
      for (int j = 0; j < 2; j++) {
        int r = mt*256 + h*128 + j*64 + trow;
        if (SEG) r = (r < cnt) ? r : (cnt - 1);
        size_t arow = SEG ? (size_t)ptok[seg + r] : (size_t)r;
        sAp[h][j] = A + arow * (size_t)K + tch * 8;
        int br = nt*256 + h*128 + j*64 + trow;
        sBp[h][j] = Bp + (size_t)br * K + tch * 8;
      }
  }

  const int wm = wave >> 2, wn = wave & 3, hb = wn >> 1;
  const int ln15 = lane & 15, kg = lane >> 4;
  const int c0 = (kg ^ (ln15 & 7)) << 4;       // read-side swizzle; ^64 flips kk
  const char* Ab0 = smem + ((0*2 + wm) << 14); // buf0 A-half(wm)
  const char* Ab1 = smem + ((1*2 + wm) << 14);
  const char* Bb0 = smem + 65536 + ((0*2 + hb) << 14);
  const char* Bb1 = smem + 65536 + ((1*2 + hb) << 14);
  const int arow0 = ln15 * 128;
  const int brow0 = ((wn & 1) * 64 + ln15) * 128;

  f32x4 acc[8][4];
  #pragma unroll
  for (int m = 0; m < 8; m++)
    #pragma unroll
    for (int n = 0; n < 4; n++) acc[m][n] = (f32x4){0,0,0,0};

  bf16x8 fa[4][2], fb[4][2];

#define STA(buf,h,kt) { size_t k_ = (size_t)(kt) * 64; \
  gload_lds16(sAp[h][0] + k_, smem + (((buf)*2+(h))<<14) + wave*1024); \
  gload_lds16(sAp[h][1] + k_, smem + (((buf)*2+(h))<<14) + 8192 + wave*1024); }
#define STB(buf,h,kt) { size_t k_ = (size_t)(kt) * 64; \
  gload_lds16(sBp[h][0] + k_, smem + 65536 + (((buf)*2+(h))<<14) + wave*1024); \
  gload_lds16(sBp[h][1] + k_, smem + 65536 + (((buf)*2+(h))<<14) + 8192 + wave*1024); }
#define LDFA(AB, qm) { _Pragma("unroll") for (int m_ = 0; m_ < 4; m_++) { \
  const char* p_ = (AB) + (qm)*8192 + m_*2048 + arow0; \
  fa[m_][0] = *(const bf16x8*)(p_ + c0); fa[m_][1] = *(const bf16x8*)(p_ + (c0 ^ 64)); } }
#define LDFB2(BB, n0) { _Pragma("unroll") for (int n_ = 0; n_ < 2; n_++) { \
  const char* p_ = (BB) + ((n0)+n_)*2048 + brow0; \
  fb[(n0)+n_][0] = *(const bf16x8*)(p_ + c0); fb[(n0)+n_][1] = *(const bf16x8*)(p_ + (c0 ^ 64)); } }
// m201-faithful phase tail: barrier -> lgkm0 -> sched_barrier -> setprio/MFMA -> barrier
#define MFMA16(QM, N0) { \
  asm volatile("" ::: "memory"); \
  __builtin_amdgcn_s_barrier(); \
  asm volatile("s_waitcnt lgkmcnt(0)" ::: "memory"); \
  __builtin_amdgcn_sched_barrier(0); \
  __builtin_amdgcn_s_setprio(1); \
  _Pragma("unroll") for (int kk_ = 0; kk_ < 2; kk_++) \
  _Pragma("unroll") for (int m_ = 0; m_ < 4; m_++) \
  _Pragma("unroll") for (int n_ = 0; n_ < 2; n_++) \
    acc[(QM)*4+m_][(N0)+n_] = __builtin_amdgcn_mfma_f32_16x16x32_bf16( \
        fa[m_][kk_], fb[(N0)+n_][kk_], acc[(QM)*4+m_][(N0)+n_], 0, 0, 0); \
  __builtin_amdgcn_s_setprio(0); \
  asm volatile("" ::: "memory"); \
  __builtin_amdgcn_s_barrier(); \
  asm volatile("" ::: "memory"); }

  // prologue: stage tile0 (4 halves) + 3 halves of tile1; drain through tile0
  STB(0,0,0); STB(0,1,0); STA(0,0,0); STA(0,1,0);
  STB(1,0,1); STB(1,1,1); STA(1,0,1);
  VM6; BAR();

  for (int t = 0; t < NKT; t += 2) {
    const bool last = (t + 2 >= NKT);
    // ph1: tile t (m0,n01); 12 ds_reads; stage A1(t+1)
    LDFB2(Bb0, 0); LDFA(Ab0, 0);
    STA(1,1,t+1);
    LGKM8;
    MFMA16(0, 0);
    // ph2: (m0,n23); 4 ds_reads; stage B0(t+2)
    LDFB2(Bb0, 2);
    if (!last) STB(0,0,t+2);
    MFMA16(0, 2);
    // ph3: (m1,n23); 8 ds_reads; stage B1(t+2)
    LDFA(Ab0, 1);
    if (!last) STB(0,1,t+2);
    MFMA16(1, 2);
    // ph4: (m1,n01); 0 ds_reads; stage A0(t+2); drain -> tile t+1 resident
    if (!last) { STA(0,0,t+2); VM6; } else { VM0; }
    MFMA16(1, 0);
    // ph5: tile t+1 (m0,n01); stage A1(t+2)
    LDFB2(Bb1, 0); LDFA(Ab1, 0);
    if (!last) STA(0,1,t+2);
    LGKM8;
    MFMA16(0, 0);
    // ph6: (m0,n23); stage B0(t+3)
    LDFB2(Bb1, 2);
    if (!last) STB(1,0,t+3);
    MFMA16(0, 2);
    // ph7: (m1,n23); stage B1(t+3)
    LDFA(Ab1, 1);
    if (!last) STB(1,1,t+3);
    MFMA16(1, 2);
    // ph8: (m1,n01); stage A0(t+3); drain -> tile t+2 resident
    if (!last) { STA(1,0,t+3); VM6; }
    MFMA16(1, 0);
  }

  // epilogue: de-interleave g/u via shfl_xor(1), SwiGLU (+bias, *pw), bf16 store
  #pragma unroll
  for (int mi = 0; mi < 8; mi++) {
    #pragma unroll
    for (int ni = 0; ni < 4; ni++) {
      int colC = nt*256 + wn*64 + ni*16 + ln15;
      int h = colC >> 1;
      int par = ln15 & 1;
      #pragma unroll
      for (int i = 0; i < 4; i++) {
        float v = acc[mi][ni][i];
        float v2 = __shfl_xor(v, 1);
        float g = par ? v2 : v;
        float uu = par ? v : v2;
        int rr = mt*256 + wm*128 + mi*16 + kg*4 + i;
        if (EPI == 1) { g += biasG[e*Hf + h]; uu += biasU[e*Hf + h]; }
        float hv = (g / (1.f + __expf(-g))) * uu;
        if (EPI == 0) {
          if (par == 0) Hout[(size_t)rr * Hf + h] = f2bf(hv);
        } else {
          if (par == 0 && rr < cnt) {
            int ai = seg + rr;
            Hout[(size_t)ai * Hf + h] = f2bf(hv * pw[ai]);
          }
        }
      }
    }
  }
#undef STA
#undef STB
#undef LDFA
#undef LDFB2
#undef MFMA16
}

// ---------------- down-projection (proven round-3 structure) ----------------
template<bool ROUTED>
__global__ __launch_bounds__(256, 2) void gemm_down(
    const u16* __restrict__ Hin, const u16* __restrict__ W,
    const float* __restrict__ B2, float* __restrict__ Out,
    const int* __restrict__ offsets, const int* __restrict__ ptok,
    const float* __restrict__ pw, int Kdim)
{
  const int nt = blockIdx.x;
  const int mt = blockIdx.y;
  int e = 0, seg = 0, cnt = NT;
  if (ROUTED) {
    e = blockIdx.z;
    seg = offsets[e];
    cnt = offsets[e+1] - seg;
    if (mt * 128 >= cnt) return;
  }
  const int m0 = mt * 128;
  const int tid = threadIdx.x;
  const int wave = tid >> 6, lane = tid & 63;

  __shared__ u16 sA[128*64];
  __shared__ u16 sB[128*64];
  char* sAc = (char*)sA;
  char* sBc = (char*)sB;

  const u16* aSrc[4]; const u16* bSrc[4];
  #pragma unroll
  for (int j = 0; j < 4; j++) {
    int c = j * 256 + tid;
    int row = c >> 3, gch = (c & 7) ^ (row & 7);
    int r = m0 + row;
    size_t arow;
    if (ROUTED) { r = (r < cnt) ? r : (cnt - 1); arow = (size_t)(seg + r); }
    else        { arow = (size_t)r; }
    aSrc[j] = Hin + arow * (size_t)Kdim + gch * 8;
    size_t brow = (size_t)(ROUTED ? e * DIM : 0) + nt * 128 + row;
    bSrc[j] = W + brow * (size_t)Kdim + gch * 8;
  }

  f32x4 acc[4][4];
  #pragma unroll
  for (int m = 0; m < 4; m++)
    #pragma unroll
    for (int n = 0; n < 4; n++) acc[m][n] = (f32x4){0,0,0,0};

  const int wr = (wave >> 1) * 64, wc = (wave & 1) * 64;
  const int lr = lane & 15, kg = lane >> 4;
  int aOff[4], bOff[4];
  #pragma unroll
  for (int m = 0; m < 4; m++) { int row = wr + m*16 + lr; aOff[m] = row*128 + ((kg ^ (row & 7)) & 7) * 16; }
  #pragma unroll
  for (int n = 0; n < 4; n++) { int row = wc + n*16 + lr; bOff[n] = row*128 + ((kg ^ (row & 7)) & 7) * 16; }

  for (int k0 = 0; k0 < Kdim; k0 += 64) {
    __syncthreads();
    #pragma unroll
    for (int j = 0; j < 4; j++) {
      gload_lds16(aSrc[j] + k0, sAc + j*4096 + wave*1024);
      gload_lds16(bSrc[j] + k0, sBc + j*4096 + wave*1024);
    }
    __syncthreads();
    bf16x8 af[4][2], bf[4][2];
    #pragma unroll
    for (int m = 0; m < 4; m++) {
      af[m][0] = *(const bf16x8*)(sAc + aOff[m]);
      af[m][1] = *(const bf16x8*)(sAc + (aOff[m] ^ 64));
    }
    #pragma unroll
    for (int n = 0; n < 4; n++) {
      bf[n][0] = *(const bf16x8*)(sBc + bOff[n]);
      bf[n][1] = *(const bf16x8*)(sBc + (bOff[n] ^ 64));
    }
    #pragma unroll
    for (int kk = 0; kk < 2; kk++)
      #pragma unroll
      for (int m = 0; m < 4; m++)
        #pragma unroll
        for (int n = 0; n < 4; n++)
          acc[m][n] = __builtin_amdgcn_mfma_f32_16x16x32_bf16(af[m][kk], bf[n][kk], acc[m][n], 0, 0, 0);
  }

  const int col0 = nt * 128 + wc;
  #pragma unroll
  for (int m = 0; m < 4; m++) {
    #pragma unroll
    for (int n = 0; n < 4; n++) {
      #pragma unroll
      for (int i = 0; i < 4; i++) {
        int rl = wr + m*16 + (lane >> 4) * 4 + i;
        int gr = m0 + rl;
        int col = col0 + n*16 + (lane & 15);
        float v = acc[m][n][i];
        if (ROUTED) {
          if (gr < cnt) {
            int ai = seg + gr;
            int token = ptok[ai];
            float w = pw[ai];
            atomicAdd(Out + (size_t)token * DIM + col, v + w * B2[e * DIM + col]);
          }
        } else {
          Out[(size_t)gr * DIM + col] = v;
        }
      }
    }
  }
}

// ---------------- launch ----------------
extern "C" void kernel_launch(void* const* d_in, const int* in_sizes, int n_in,
                              void* d_out, int out_size, void* d_ws, size_t ws_size,
                              hipStream_t stream) {
  (void)in_sizes; (void)n_in; (void)out_size; (void)ws_size;
  const float* x      = (const float*)d_in[0];
  const float* gate_w = (const float*)d_in[1];
  const float* gate_b = (const float*)d_in[2];
  const float* w1     = (const float*)d_in[3];
  const float* b1     = (const float*)d_in[4];
  const float* w3     = (const float*)d_in[5];
  const float* b3     = (const float*)d_in[6];
  const float* w2     = (const float*)d_in[7];
  const float* b2     = (const float*)d_in[8];
  const float* shg    = (const float*)d_in[9];
  const float* shu    = (const float*)d_in[10];
  const float* shd    = (const float*)d_in[11];
  float* out = (float*)d_out;

  char* ws = (char*)d_ws;
  size_t off = 0;
  auto alloc = [&](size_t bytes) -> void* {
    void* p = ws + off;
    off += (bytes + 255) & ~(size_t)255;
    return p;
  };
  u16* xb    = (u16*)alloc((size_t)NT * DIM * 2);
  u16* wupr  = (u16*)alloc((size_t)NEXP * 2 * NH * DIM * 2);  // interleaved w1/w3
  u16* w2b   = (u16*)alloc((size_t)NEXP * DIM * NH * 2);
  u16* wupsh = (u16*)alloc((size_t)2 * NHS * DIM * 2);        // interleaved shg/shu
  u16* shdb  = (u16*)alloc((size_t)DIM * NHS * 2);
  u16* hsh   = (u16*)alloc((size_t)NT * NHS * 2);
  u16* hr    = (u16*)alloc((size_t)NA * NH * 2);
  int*   tope    = (int*)alloc(NT * 2 * 4);
  float* topw    = (float*)alloc(NT * 2 * 4);
  int*   ptok    = (int*)alloc(NA * 4);
  float* pw      = (float*)alloc(NA * 4);
  int*   counts  = (int*)alloc(64);
  int*   offsets = (int*)alloc(64);
  int*   cursor  = (int*)alloc(64);

  (void)hipFuncSetAttribute((const void*)gemm8<0>, hipFuncAttributeMaxDynamicSharedMemorySize, 131072);
  (void)hipFuncSetAttribute((const void*)gemm8<1>, hipFuncAttributeMaxDynamicSharedMemorySize, 131072);

  auto cvt = [&](const float* s, u16* d, size_t n) {
    int n8 = (int)(n / 8);
    convert_kernel<<<(n8 + 255) / 256, 256, 0, stream>>>(s, d, n8);
  };
  auto cvi = [&](const float* s, u16* d, size_t n, int par) {
    int n8 = (int)(n / 8);
    convert_ilv<<<(n8 + 255) / 256, 256, 0, stream>>>(s, d, n8, par);
  };
  cvi(w1,  wupr,  (size_t)NEXP * NH * DIM, 0);
  cvi(w3,  wupr,  (size_t)NEXP * NH * DIM, 1);
  cvt(w2,  w2b,   (size_t)NEXP * DIM * NH);
  cvi(shg, wupsh, (size_t)NHS * DIM, 0);
  cvi(shu, wupsh, (size_t)NHS * DIM, 1);
  cvt(shd, shdb,  (size_t)DIM * NHS);

  zero_counts<<<1, 64, 0, stream>>>(counts);
  router_kernel<<<NT, 64, 0, stream>>>(x, gate_w, gate_b, xb, tope, topw, counts);
  scan_kernel<<<1, 1, 0, stream>>>(counts, offsets, cursor);
  assign_kernel<<<NT / 256, 256, 0, stream>>>(tope, topw, cursor, ptok, pw);

  // shared up: A=xb [8192x2048], B=wupsh [5632x2048] -> hsh bf16 [8192x2816]
  gemm8<0><<<dim3(2*NHS/256, NT/256, 1), 512, 131072, stream>>>(
      xb, wupsh, hsh, nullptr, nullptr, nullptr, nullptr, nullptr,
      NT, 2*NHS, DIM, NHS);
  // routed up: A=xb gathered, B=wupr [e][2816x2048] -> hr bf16 [NA x 1408]
  gemm8<1><<<dim3(2*NH/256, NT/256, NEXP), 512, 131072, stream>>>(
      xb, wupr, hr, b1, b3, offsets, ptok, pw,
      NT, 2*NH, DIM, NH);
  // shared down writes out, then routed down atomically accumulates
  gemm_down<false><<<dim3(DIM / 128, NT / 128, 1), 256, 0, stream>>>(
      hsh, shdb, nullptr, out, nullptr, nullptr, nullptr, NHS);
  gemm_down<true><<<dim3(DIM / 128, NT / 128, NEXP), 256, 0, stream>>>(
      hr, w2b, b2, out, offsets, ptok, pw, NH);
}

// Round 9
// 1106.087 us; speedup vs baseline: 1.0970x; 1.0970x over previous
//
#include <hip/hip_runtime.h>
#include <stdint.h>

#define DIM  2048
#define NEXP 8
#define NH   1408
#define NHS  2816
#define NT   8192
#define NA   (NT*2)

typedef unsigned short u16;
typedef short bf16x8 __attribute__((ext_vector_type(8)));
typedef float f32x4 __attribute__((ext_vector_type(4)));

typedef __attribute__((address_space(1))) const uint32_t gas_u32;
typedef __attribute__((address_space(3))) uint32_t las_u32;

__device__ __forceinline__ u16 f2bf(float f) {
  uint32_t x = __builtin_bit_cast(uint32_t, f);
  x += 0x7FFFu + ((x >> 16) & 1u);
  return (u16)(x >> 16);
}

__device__ __forceinline__ void gload_lds16(const void* g, void* l) {
  __builtin_amdgcn_global_load_lds((gas_u32*)g, (las_u32*)l, 16, 0, 0);
}

// Corrected XCD-aware remap (T1 done right):
// Each XCD owns a CONTIGUOUS band of the G *active* M-tiles (band computed
// device-side from cnt so routed kernels stay balanced), iterated mt-inner /
// nt-outer so concurrently-resident blocks on one XCD share a single L2-sized
// A-band and a small set of B-panels (round-4's striped mt%8 gave concurrent
// blocks disjoint A-strips -> latency regression).
// Returns false for inactive/unused slots.
__device__ __forceinline__ bool xcd_map_band(int G, int& nt, int& mt) {
  const int gx = gridDim.x;
  int f = blockIdx.y * gx + blockIdx.x;   // z-plane sizes are %8==0 -> phase kept
  int xcd = f & 7;
  int local = f >> 3;
  if (G <= 0) return false;
  int band = (G + 7) >> 3;                // active M-tiles per XCD
  int slot = local % band;
  int ntv  = local / band;
  if (ntv >= gx) return false;
  int mtv = xcd * band + slot;
  if (mtv >= G) return false;
  nt = ntv; mt = mtv;
  return true;
}

struct alignas(16) US8 { u16 u[8]; };
struct alignas(8)  US4 { u16 u[4]; };

// ---------------- fp32 -> bf16 conversion (weights) ----------------
__global__ __launch_bounds__(256) void convert_kernel(const float* __restrict__ src,
                                                      u16* __restrict__ dst, int n8) {
  int i = blockIdx.x * 256 + threadIdx.x;
  if (i >= n8) return;
  const float4* s = (const float4*)src + (size_t)i * 2;
  float4 a = s[0], b = s[1];
  US8 r;
  r.u[0]=f2bf(a.x); r.u[1]=f2bf(a.y); r.u[2]=f2bf(a.z); r.u[3]=f2bf(a.w);
  r.u[4]=f2bf(b.x); r.u[5]=f2bf(b.y); r.u[6]=f2bf(b.z); r.u[7]=f2bf(b.w);
  *((US8*)dst + i) = r;
}

// ---------------- router (fused: also emits x as bf16) ----------------
__global__ void zero_counts(int* counts) { if (threadIdx.x < NEXP) counts[threadIdx.x] = 0; }

__global__ __launch_bounds__(64) void router_kernel(const float* __restrict__ x,
    const float* __restrict__ gw, const float* __restrict__ gb,
    u16* __restrict__ xb,
    int* __restrict__ tope, float* __restrict__ topw, int* __restrict__ counts) {
  const int t = blockIdx.x;
  const int lane = threadIdx.x;
  const float4* xr = (const float4*)(x + (size_t)t * DIM);
  float4 xv[8];
  #pragma unroll
  for (int j = 0; j < 8; j++) xv[j] = xr[j * 64 + lane];
  US4* xrow = (US4*)(xb + (size_t)t * DIM);
  #pragma unroll
  for (int j = 0; j < 8; j++) {
    US4 r4;
    r4.u[0] = f2bf(xv[j].x); r4.u[1] = f2bf(xv[j].y);
    r4.u[2] = f2bf(xv[j].z); r4.u[3] = f2bf(xv[j].w);
    xrow[j * 64 + lane] = r4;
  }
  float p[NEXP];
  #pragma unroll
  for (int e = 0; e < NEXP; e++) {
    const float4* gr = (const float4*)(gw + (size_t)e * DIM);
    float s = 0.f;
    #pragma unroll
    for (int j = 0; j < 8; j++) {
      float4 g = gr[j * 64 + lane];
      s += xv[j].x*g.x + xv[j].y*g.y + xv[j].z*g.z + xv[j].w*g.w;
    }
    p[e] = s;
  }
  #pragma unroll
  for (int off = 32; off > 0; off >>= 1) {
    #pragma unroll
    for (int e = 0; e < NEXP; e++) p[e] += __shfl_xor(p[e], off);
  }
  if (lane == 0) {
    float pr[NEXP];
    float mx = -1e30f;
    #pragma unroll
    for (int e = 0; e < NEXP; e++) { p[e] += gb[e]; mx = fmaxf(mx, p[e]); }
    float den = 0.f;
    #pragma unroll
    for (int e = 0; e < NEXP; e++) { pr[e] = __expf(p[e] - mx); den += pr[e]; }
    float inv = 1.f / den;
    #pragma unroll
    for (int e = 0; e < NEXP; e++) pr[e] *= inv;
    int e0 = 0;
    #pragma unroll
    for (int e = 1; e < NEXP; e++) if (pr[e] > pr[e0]) e0 = e;
    int e1 = (e0 == 0) ? 1 : 0;
    #pragma unroll
    for (int e = 0; e < NEXP; e++) { if (e != e0 && pr[e] > pr[e1]) e1 = e; }
    tope[t*2]   = e0; tope[t*2+1] = e1;
    topw[t*2]   = pr[e0]; topw[t*2+1] = pr[e1];
    atomicAdd(&counts[e0], 1); atomicAdd(&counts[e1], 1);
  }
}

__global__ void scan_kernel(const int* __restrict__ counts, int* __restrict__ offsets,
                            int* __restrict__ cursor) {
  if (threadIdx.x == 0) {
    int s = 0;
    for (int e = 0; e < NEXP; e++) { offsets[e] = s; cursor[e] = s; s += counts[e]; }
    offsets[NEXP] = s;
  }
}

__global__ __launch_bounds__(256) void assign_kernel(const int* __restrict__ tope,
    const float* __restrict__ topw, int* __restrict__ cursor,
    int* __restrict__ ptok, float* __restrict__ pw) {
  int t = blockIdx.x * 256 + threadIdx.x;
  if (t >= NT) return;
  #pragma unroll
  for (int k = 0; k < 2; k++) {
    int e = tope[t*2+k];
    int pos = atomicAdd(&cursor[e], 1);
    ptok[pos] = t;
    pw[pos]   = topw[t*2+k];
  }
}

// ---------------- fused up-projection (gate & up), SwiGLU epilogue ----------------
// C tile: 128 rows x 64 cols of BOTH matrices. BK=64. K = DIM. (round-3 proven)
template<bool ROUTED>
__global__ __launch_bounds__(256, 2) void gemm_up(
    const u16* __restrict__ X,    // [NT, DIM] bf16
    const u16* __restrict__ Wg,   // [(E*)N, DIM]
    const u16* __restrict__ Wu,
    const float* __restrict__ Bg, // [E, N] or null
    const float* __restrict__ Bu,
    u16* __restrict__ Hout,       // [rows, N]
    const int* __restrict__ offsets,
    const int* __restrict__ ptok,
    const float* __restrict__ pw,
    int Nfeat)
{
  int e = 0, seg = 0, cnt = NT;
  if (ROUTED) {
    e = blockIdx.z;
    seg = offsets[e];
    cnt = offsets[e+1] - seg;
  }
  const int G = ROUTED ? ((cnt + 127) >> 7) : (int)gridDim.y;
  int nt, mt;
  if (!xcd_map_band(G, nt, mt)) return;
  const int m0 = mt * 128;
  const int tid = threadIdx.x;
  const int wave = tid >> 6, lane = tid & 63;

  __shared__ u16 sA[128*64];
  __shared__ u16 sBg[64*64];
  __shared__ u16 sBu[64*64];
  char* sAc  = (char*)sA;
  char* sBgc = (char*)sBg;
  char* sBuc = (char*)sBu;

  // A staging: 128 rows x 8 chunks; 4 chunks/thread. LDS linear dest; global src
  // pre-inverse-swizzled: LDS chunk p of row r holds global chunk p^(r&7).
  const u16* aSrc[4];
  #pragma unroll
  for (int j = 0; j < 4; j++) {
    int c = j * 256 + tid;
    int row = c >> 3, gch = (c & 7) ^ (row & 7);
    int r = m0 + row;
    size_t srow;
    if (ROUTED) { r = (r < cnt) ? r : (cnt - 1); srow = (size_t)ptok[seg + r]; }
    else        { srow = (size_t)r; }
    aSrc[j] = X + srow * DIM + gch * 8;
  }
  // B staging: 64 rows x 8 chunks; 2 chunks/thread per matrix
  const size_t wOff = ROUTED ? (size_t)e * Nfeat * DIM : 0;
  const u16 *bgSrc[2], *buSrc[2];
  #pragma unroll
  for (int j = 0; j < 2; j++) {
    int c = j * 256 + tid;
    int row = c >> 3, gch = (c & 7) ^ (row & 7);
    bgSrc[j] = Wg + wOff + (size_t)(nt * 64 + row) * DIM + gch * 8;
    buSrc[j] = Wu + wOff + (size_t)(nt * 64 + row) * DIM + gch * 8;
  }

  f32x4 accg[4][2], accu[4][2];
  #pragma unroll
  for (int m = 0; m < 4; m++)
    #pragma unroll
    for (int n = 0; n < 2; n++) { accg[m][n] = (f32x4){0,0,0,0}; accu[m][n] = (f32x4){0,0,0,0}; }

  const int wr = (wave >> 1) * 64;
  const int wc = (wave & 1) * 32;
  const int lr = lane & 15, kg = lane >> 4;
  int aOff[4], bOff[2];
  #pragma unroll
  for (int m = 0; m < 4; m++) { int row = wr + m*16 + lr; aOff[m] = row*128 + ((kg ^ (row & 7)) & 7) * 16; }
  #pragma unroll
  for (int n = 0; n < 2; n++) { int row = wc + n*16 + lr; bOff[n] = row*128 + ((kg ^ (row & 7)) & 7) * 16; }

  for (int k0 = 0; k0 < DIM; k0 += 64) {
    __syncthreads();
    #pragma unroll
    for (int j = 0; j < 4; j++) gload_lds16(aSrc[j] + k0, sAc + j*4096 + wave*1024);
    #pragma unroll
    for (int j = 0; j < 2; j++) {
      gload_lds16(bgSrc[j] + k0, sBgc + j*4096 + wave*1024);
      gload_lds16(buSrc[j] + k0, sBuc + j*4096 + wave*1024);
    }
    __syncthreads();
    bf16x8 af[4][2], bgf[2][2], buf2[2][2];
    #pragma unroll
    for (int m = 0; m < 4; m++) {
      af[m][0] = *(const bf16x8*)(sAc + aOff[m]);
      af[m][1] = *(const bf16x8*)(sAc + (aOff[m] ^ 64));
    }
    #pragma unroll
    for (int n = 0; n < 2; n++) {
      bgf[n][0]  = *(const bf16x8*)(sBgc + bOff[n]);
      bgf[n][1]  = *(const bf16x8*)(sBgc + (bOff[n] ^ 64));
      buf2[n][0] = *(const bf16x8*)(sBuc + bOff[n]);
      buf2[n][1] = *(const bf16x8*)(sBuc + (bOff[n] ^ 64));
    }
    #pragma unroll
    for (int kk = 0; kk < 2; kk++)
      #pragma unroll
      for (int m = 0; m < 4; m++)
        #pragma unroll
        for (int n = 0; n < 2; n++) {
          accg[m][n] = __builtin_amdgcn_mfma_f32_16x16x32_bf16(af[m][kk], bgf[n][kk],  accg[m][n], 0, 0, 0);
          accu[m][n] = __builtin_amdgcn_mfma_f32_16x16x32_bf16(af[m][kk], buf2[n][kk], accu[m][n], 0, 0, 0);
        }
  }

  // epilogue: SwiGLU (+bias, +routing weight), write bf16 hidden
  const int col0 = nt * 64 + wc;
  #pragma unroll
  for (int m = 0; m < 4; m++) {
    #pragma unroll
    for (int n = 0; n < 2; n++) {
      #pragma unroll
      for (int i = 0; i < 4; i++) {
        int rl = wr + m*16 + (lane >> 4) * 4 + i;
        int gr = m0 + rl;
        if (ROUTED && gr >= cnt) continue;
        int col = col0 + n*16 + (lane & 15);
        float g = accg[m][n][i];
        float u = accu[m][n][i];
        float scale = 1.f;
        size_t orow;
        if (ROUTED) {
          int ai = seg + gr;
          scale = pw[ai];
          g += Bg[e * Nfeat + col];
          u += Bu[e * Nfeat + col];
          orow = (size_t)ai;
        } else {
          orow = (size_t)gr;
        }
        float s = g / (1.f + __expf(-g));
        Hout[orow * (size_t)Nfeat + col] = f2bf(s * u * scale);
      }
    }
  }
}

// ---------------- down-projection ----------------
// C tile: 128 x 128. BK=64. K = Kdim (NH or NHS). N = DIM. (round-3 proven)
template<bool ROUTED>
__global__ __launch_bounds__(256, 2) void gemm_down(
    const u16* __restrict__ Hin,  // [rows, Kdim] bf16
    const u16* __restrict__ W,    // [(E*)DIM, Kdim]
    const float* __restrict__ B2, // [E, DIM] or null
    float* __restrict__ Out,      // [NT, DIM]
    const int* __restrict__ offsets,
    const int* __restrict__ ptok,
    const float* __restrict__ pw,
    int Kdim)
{
  int e = 0, seg = 0, cnt = NT;
  if (ROUTED) {
    e = blockIdx.z;
    seg = offsets[e];
    cnt = offsets[e+1] - seg;
  }
  const int G = ROUTED ? ((cnt + 127) >> 7) : (int)gridDim.y;
  int nt, mt;
  if (!xcd_map_band(G, nt, mt)) return;
  const int m0 = mt * 128;
  const int tid = threadIdx.x;
  const int wave = tid >> 6, lane = tid & 63;

  __shared__ u16 sA[128*64];
  __shared__ u16 sB[128*64];
  char* sAc = (char*)sA;
  char* sBc = (char*)sB;

  const u16* aSrc[4]; const u16* bSrc[4];
  #pragma unroll
  for (int j = 0; j < 4; j++) {
    int c = j * 256 + tid;
    int row = c >> 3, gch = (c & 7) ^ (row & 7);
    int r = m0 + row;
    size_t arow;
    if (ROUTED) { r = (r < cnt) ? r : (cnt - 1); arow = (size_t)(seg + r); }
    else        { arow = (size_t)r; }
    aSrc[j] = Hin + arow * (size_t)Kdim + gch * 8;
    size_t brow = (size_t)(ROUTED ? e * DIM : 0) + nt * 128 + row;
    bSrc[j] = W + brow * (size_t)Kdim + gch * 8;
  }

  f32x4 acc[4][4];
  #pragma unroll
  for (int m = 0; m < 4; m++)
    #pragma unroll
    for (int n = 0; n < 4; n++) acc[m][n] = (f32x4){0,0,0,0};

  const int wr = (wave >> 1) * 64, wc = (wave & 1) * 64;
  const int lr = lane & 15, kg = lane >> 4;
  int aOff[4], bOff[4];
  #pragma unroll
  for (int m = 0; m < 4; m++) { int row = wr + m*16 + lr; aOff[m] = row*128 + ((kg ^ (row & 7)) & 7) * 16; }
  #pragma unroll
  for (int n = 0; n < 4; n++) { int row = wc + n*16 + lr; bOff[n] = row*128 + ((kg ^ (row & 7)) & 7) * 16; }

  for (int k0 = 0; k0 < Kdim; k0 += 64) {
    __syncthreads();
    #pragma unroll
    for (int j = 0; j < 4; j++) {
      gload_lds16(aSrc[j] + k0, sAc + j*4096 + wave*1024);
      gload_lds16(bSrc[j] + k0, sBc + j*4096 + wave*1024);
    }
    __syncthreads();
    bf16x8 af[4][2], bf[4][2];
    #pragma unroll
    for (int m = 0; m < 4; m++) {
      af[m][0] = *(const bf16x8*)(sAc + aOff[m]);
      af[m][1] = *(const bf16x8*)(sAc + (aOff[m] ^ 64));
    }
    #pragma unroll
    for (int n = 0; n < 4; n++) {
      bf[n][0] = *(const bf16x8*)(sBc + bOff[n]);
      bf[n][1] = *(const bf16x8*)(sBc + (bOff[n] ^ 64));
    }
    #pragma unroll
    for (int kk = 0; kk < 2; kk++)
      #pragma unroll
      for (int m = 0; m < 4; m++)
        #pragma unroll
        for (int n = 0; n < 4; n++)
          acc[m][n] = __builtin_amdgcn_mfma_f32_16x16x32_bf16(af[m][kk], bf[n][kk], acc[m][n], 0, 0, 0);
  }

  const int col0 = nt * 128 + wc;
  #pragma unroll
  for (int m = 0; m < 4; m++) {
    #pragma unroll
    for (int n = 0; n < 4; n++) {
      #pragma unroll
      for (int i = 0; i < 4; i++) {
        int rl = wr + m*16 + (lane >> 4) * 4 + i;
        int gr = m0 + rl;
        int col = col0 + n*16 + (lane & 15);
        float v = acc[m][n][i];
        if (ROUTED) {
          if (gr < cnt) {
            int ai = seg + gr;
            int token = ptok[ai];
            float w = pw[ai];
            atomicAdd(Out + (size_t)token * DIM + col, v + w * B2[e * DIM + col]);
          }
        } else {
          Out[(size_t)gr * DIM + col] = v;
        }
      }
    }
  }
}

// ---------------- launch ----------------
extern "C" void kernel_launch(void* const* d_in, const int* in_sizes, int n_in,
                              void* d_out, int out_size, void* d_ws, size_t ws_size,
                              hipStream_t stream) {
  (void)in_sizes; (void)n_in; (void)out_size; (void)ws_size;
  const float* x      = (const float*)d_in[0];
  const float* gate_w = (const float*)d_in[1];
  const float* gate_b = (const float*)d_in[2];
  const float* w1     = (const float*)d_in[3];
  const float* b1     = (const float*)d_in[4];
  const float* w3     = (const float*)d_in[5];
  const float* b3     = (const float*)d_in[6];
  const float* w2     = (const float*)d_in[7];
  const float* b2     = (const float*)d_in[8];
  const float* shg    = (const float*)d_in[9];
  const float* shu    = (const float*)d_in[10];
  const float* shd    = (const float*)d_in[11];
  float* out = (float*)d_out;

  char* ws = (char*)d_ws;
  size_t off = 0;
  auto alloc = [&](size_t bytes) -> void* {
    void* p = ws + off;
    off += (bytes + 255) & ~(size_t)255;
    return p;
  };
  u16* xb    = (u16*)alloc((size_t)NT * DIM * 2);
  u16* w1b   = (u16*)alloc((size_t)NEXP * NH * DIM * 2);
  u16* w3b   = (u16*)alloc((size_t)NEXP * NH * DIM * 2);
  u16* w2b   = (u16*)alloc((size_t)NEXP * DIM * NH * 2);
  u16* shgb  = (u16*)alloc((size_t)NHS * DIM * 2);
  u16* shub  = (u16*)alloc((size_t)NHS * DIM * 2);
  u16* shdb  = (u16*)alloc((size_t)DIM * NHS * 2);
  u16* hsh   = (u16*)alloc((size_t)NT * NHS * 2);
  u16* hr    = (u16*)alloc((size_t)NA * NH * 2);
  int*   tope    = (int*)alloc(NT * 2 * 4);
  float* topw    = (float*)alloc(NT * 2 * 4);
  int*   ptok    = (int*)alloc(NA * 4);
  float* pw      = (float*)alloc(NA * 4);
  int*   counts  = (int*)alloc(64);
  int*   offsets = (int*)alloc(64);
  int*   cursor  = (int*)alloc(64);

  auto cvt = [&](const float* s, u16* d, size_t n) {
    int n8 = (int)(n / 8);
    convert_kernel<<<(n8 + 255) / 256, 256, 0, stream>>>(s, d, n8);
  };
  cvt(w1,  w1b,  (size_t)NEXP * NH * DIM);
  cvt(w3,  w3b,  (size_t)NEXP * NH * DIM);
  cvt(w2,  w2b,  (size_t)NEXP * DIM * NH);
  cvt(shg, shgb, (size_t)NHS * DIM);
  cvt(shu, shub, (size_t)NHS * DIM);
  cvt(shd, shdb, (size_t)DIM * NHS);

  zero_counts<<<1, 64, 0, stream>>>(counts);
  router_kernel<<<NT, 64, 0, stream>>>(x, gate_w, gate_b, xb, tope, topw, counts);
  scan_kernel<<<1, 1, 0, stream>>>(counts, offsets, cursor);
  assign_kernel<<<NT / 256, 256, 0, stream>>>(tope, topw, cursor, ptok, pw);

  // shared expert: up (fused SwiGLU) then down (plain store initializes out)
  gemm_up<false><<<dim3(NHS / 64, NT / 128, 1), 256, 0, stream>>>(
      xb, shgb, shub, nullptr, nullptr, hsh, nullptr, nullptr, nullptr, NHS);
  // routed experts: up (fused SwiGLU * routing weight)
  gemm_up<true><<<dim3(NH / 64, NT / 128, NEXP), 256, 0, stream>>>(
      xb, w1b, w3b, b1, b3, hr, offsets, ptok, pw, NH);
  // shared down writes out, then routed down atomically accumulates
  gemm_down<false><<<dim3(DIM / 128, NT / 128, 1), 256, 0, stream>>>(
      hsh, shdb, nullptr, out, nullptr, nullptr, nullptr, NHS);
  gemm_down<true><<<dim3(DIM / 128, NT / 128, NEXP), 256, 0, stream>>>(
      hr, w2b, b2, out, offsets, ptok, pw, NH);
}